// Round 1
// baseline (243.324 us; speedup 1.0000x reference)
//
#include <hip/hip_runtime.h>
#include <math.h>

// Accumulators in workspace (d_ws is poisoned to 0xAA before every launch,
// so init_kernel must re-zero every call).
struct Acc {
  double sum3;   // sum_i (h3[i] - log_risk3[i]) * censor[i]
  double sum1;   // sum_i (h1[i] - log_risk1[i]) * censor[i]
  double tot_l;  // lgg pair-term sum
  double tot_h;  // hgg pair-term sum
  unsigned long long n_l;
  unsigned long long n_h;
};

__device__ const float RISK_TABLE_D[9] = {1.0f, 1.0f, 0.91f, 1.12f, 1.71f,
                                          2.41f, 3.27f, 5.18f, 8.44f};

__global__ void init_kernel(Acc* acc) {
  if (threadIdx.x == 0) {
    acc->sum3 = 0.0;
    acc->sum1 = 0.0;
    acc->tot_l = 0.0;
    acc->tot_h = 0.0;
    acc->n_l = 0ull;
    acc->n_h = 0ull;
  }
}

// Per-element risk lookup + pair-eligibility flags.
// bit0: lgg "i-side"  (age < 40  && grade == 0)
// bit1: lgg "j-side"  (age >= 40 && grade == 0)
// bit2: hgg "i-side"  (age < 65  && grade in {1,2})
// bit3: hgg "j-side"  (age >= 65 && grade in {1,2})
__global__ void prep_kernel(const int* __restrict__ age,
                            const int* __restrict__ grade,
                            float* __restrict__ risk,
                            int* __restrict__ flags, int B) {
  int i = blockIdx.x * blockDim.x + threadIdx.x;
  if (i >= B) return;
  int a = age[i];
  int b = a / 10;
  b = b < 0 ? 0 : (b > 8 ? 8 : b);
  risk[i] = RISK_TABLE_D[b];
  int g = grade[i];
  bool g0 = (g == 0);
  bool g12 = (g == 1) || (g == 2);
  int f = 0;
  if (g0 && a < 40) f |= 1;
  if (g0 && a >= 40) f |= 2;
  if (g12 && a < 65) f |= 4;
  if (g12 && a >= 65) f |= 8;
  flags[i] = f;
}

// Fused kernel: one block per row i.
//  - online logsumexp over {j : survtime[j] >= survtime[i]} for h3 and h1
//  - pair-rank terms for j > i matching lgg/hgg masks
__global__ __launch_bounds__(256) void main_kernel(
    const float* __restrict__ h3, const float* __restrict__ h1,
    const float* __restrict__ st, const float* __restrict__ cen,
    const float* __restrict__ risk, const int* __restrict__ flags,
    const float* __restrict__ beta1p, const float* __restrict__ beta2p,
    Acc* __restrict__ acc, int B) {
  const int i = blockIdx.x;
  const int tid = threadIdx.x;

  const float s_i = st[i];
  const float h3i = h3[i];
  const float h1i = h1[i];
  const float ri = risk[i];
  const int fi = flags[i];
  const float b1 = beta1p[0];
  const float b2 = beta2p[0];

  // per-thread online logsumexp state
  float m3 = -INFINITY, s3 = 0.f;
  float m1 = -INFINITY, s1 = 0.f;
  // per-thread pair sums
  float tl = 0.f, th = 0.f;
  unsigned int nl = 0u, nh = 0u;

  const bool any_pair = (fi & (1 | 4)) != 0;

  for (int j = tid; j < B; j += 256) {
    float stj = st[j];
    if (stj >= s_i) {
      float x = h3[j];
      if (x > m3) {
        s3 = s3 * expf(m3 - x) + 1.f;
        m3 = x;
      } else {
        s3 += expf(x - m3);
      }
      float y = h1[j];
      if (y > m1) {
        s1 = s1 * expf(m1 - y) + 1.f;
        m1 = y;
      } else {
        s1 += expf(y - m1);
      }
    }
    if (any_pair && j > i) {
      int fj = flags[j];
      bool lg = (fi & 1) && (fj & 2);
      bool hg = (fi & 4) && (fj & 8);
      if (lg || hg) {  // disjoint: grade sets don't overlap
        float beta = lg ? b1 : b2;
        float d = (risk[j] - ri) * 0.125f;
        float alpha = d / (1.f + expf(-beta * d));  // swish(d, beta)
        float x = alpha * (h3i - h3[j]);
        // stable softplus = max(x,0) + log1p(exp(-|x|))  (== jax.nn.softplus)
        float ax = fabsf(x);
        float t = fmaxf(x, 0.f) + log1pf(expf(-ax));
        if (lg) {
          tl += t;
          nl++;
        } else {
          th += t;
          nh++;
        }
      }
    }
  }

  // ---- block reductions ----
  __shared__ float red_m[256];
  __shared__ float red_s[256];
  __shared__ float red_a[256];
  __shared__ float red_b[256];
  __shared__ unsigned int red_nl[256];
  __shared__ unsigned int red_nh[256];

  // logsumexp combine for h3
  red_m[tid] = m3;
  red_s[tid] = s3;
  red_a[tid] = tl;
  red_b[tid] = th;
  red_nl[tid] = nl;
  red_nh[tid] = nh;
  __syncthreads();
  for (int off = 128; off > 0; off >>= 1) {
    if (tid < off) {
      float ma = red_m[tid], sa = red_s[tid];
      float mb = red_m[tid + off], sb = red_s[tid + off];
      if (mb > ma) {
        float tmp = ma; ma = mb; mb = tmp;
        tmp = sa; sa = sb; sb = tmp;
      }
      if (mb != -INFINITY) sa += sb * expf(mb - ma);
      red_m[tid] = ma;
      red_s[tid] = sa;
      red_a[tid] += red_a[tid + off];
      red_b[tid] += red_b[tid + off];
      red_nl[tid] += red_nl[tid + off];
      red_nh[tid] += red_nh[tid + off];
    }
    __syncthreads();
  }
  float logr3 = 0.f;
  if (tid == 0) logr3 = red_m[0] + logf(red_s[0]);
  __syncthreads();

  // logsumexp combine for h1 (reuse arrays)
  red_m[tid] = m1;
  red_s[tid] = s1;
  __syncthreads();
  for (int off = 128; off > 0; off >>= 1) {
    if (tid < off) {
      float ma = red_m[tid], sa = red_s[tid];
      float mb = red_m[tid + off], sb = red_s[tid + off];
      if (mb > ma) {
        float tmp = ma; ma = mb; mb = tmp;
        tmp = sa; sa = sb; sb = tmp;
      }
      if (mb != -INFINITY) sa += sb * expf(mb - ma);
      red_m[tid] = ma;
      red_s[tid] = sa;
    }
    __syncthreads();
  }

  if (tid == 0) {
    float logr1 = red_m[0] + logf(red_s[0]);
    float c = cen[i];
    atomicAdd(&acc->sum3, (double)((h3i - logr3) * c));
    atomicAdd(&acc->sum1, (double)((h1i - logr1) * c));
    if (red_a[0] != 0.f) atomicAdd(&acc->tot_l, (double)red_a[0]);
    if (red_b[0] != 0.f) atomicAdd(&acc->tot_h, (double)red_b[0]);
    if (red_nl[0]) atomicAdd(&acc->n_l, (unsigned long long)red_nl[0]);
    if (red_nh[0]) atomicAdd(&acc->n_h, (unsigned long long)red_nh[0]);
  }
}

__global__ void final_kernel(const Acc* __restrict__ acc,
                             const float* __restrict__ vars,
                             float* __restrict__ out, int B) {
  if (threadIdx.x != 0 || blockIdx.x != 0) return;
  float loss3d = (float)(-acc->sum3 / (double)B);
  float loss1d = (float)(-acc->sum1 / (double)B);
  float lgg = (acc->n_l > 0) ? (float)(acc->tot_l / (double)acc->n_l) : 0.f;
  float hgg = (acc->n_h > 0) ? (float)(acc->tot_h / (double)acc->n_h) : 0.f;
  float losscli = lgg + hgg;
  float v0 = vars[0], v2 = vars[2], v3 = vars[3];
  float r = 0.5f * loss3d / (v0 * v0) + logf(v0);
  r += 0.5f * loss1d / (v2 * v2) + logf(v2);
  r += 0.5f * losscli / (v3 * v3) + logf(v3);
  out[0] = r;
}

extern "C" void kernel_launch(void* const* d_in, const int* in_sizes, int n_in,
                              void* d_out, int out_size, void* d_ws,
                              size_t ws_size, hipStream_t stream) {
  const float* h3 = (const float*)d_in[0];
  const float* h1 = (const float*)d_in[1];
  const float* st = (const float*)d_in[2];
  const float* cen = (const float*)d_in[3];
  const float* vars = (const float*)d_in[4];
  const float* beta1 = (const float*)d_in[5];
  const float* beta2 = (const float*)d_in[6];
  const int* age = (const int*)d_in[7];
  const int* grade = (const int*)d_in[8];
  const int B = in_sizes[0];

  // workspace layout: Acc (64B aligned) | risk[B] float | flags[B] int
  char* ws = (char*)d_ws;
  Acc* acc = (Acc*)ws;
  float* risk = (float*)(ws + 64);
  int* flags = (int*)(ws + 64 + ((size_t)B * 4));

  float* out = (float*)d_out;

  init_kernel<<<1, 64, 0, stream>>>(acc);
  prep_kernel<<<(B + 255) / 256, 256, 0, stream>>>(age, grade, risk, flags, B);
  main_kernel<<<B, 256, 0, stream>>>(h3, h1, st, cen, risk, flags, beta1,
                                     beta2, acc, B);
  final_kernel<<<1, 64, 0, stream>>>(acc, vars, out, B);
}

// Round 2
// 145.806 us; speedup vs baseline: 1.6688x; 1.6688x over previous
//
#include <hip/hip_runtime.h>
#include <math.h>

#define NBUK 4096
#define TPB 1024
#define NPAIRB 64

// ws layout: [0,64) Acc | [64,80) cnt4 | [128,16512) bcnt[4096] |
//            [16512..) 4 pair lists (ushort[4096] each). First 16512 B zeroed
//            via hipMemsetAsync each launch (ws is re-poisoned by harness).
struct Acc {
  double sum3, sum1, tot_l, tot_h;
  unsigned long long n_l, n_h;
  unsigned int done;
  unsigned int pad;
};

__device__ __forceinline__ float riskOf(int a) {
  int d = a / 10;
  d = d > 8 ? 8 : (d < 0 ? 0 : d);
  float r = 1.0f;                 // decades 0,1
  r = (d == 2) ? 0.91f : r;
  r = (d == 3) ? 1.12f : r;
  r = (d == 4) ? 1.71f : r;
  r = (d == 5) ? 2.41f : r;
  r = (d == 6) ? 3.27f : r;
  r = (d == 7) ? 5.18f : r;
  r = (d == 8) ? 8.44f : r;
  return r;
}

__device__ __forceinline__ int bucketOf(float s) {
  // s in [0,1); *4096 is exact (power-of-two scale) => monotone bucketing
  int b = (int)(s * (float)NBUK);
  return b < 0 ? 0 : (b >= NBUK ? NBUK - 1 : b);
}

__device__ __forceinline__ double wredsum(double v) {
  for (int off = 32; off; off >>= 1) v += __shfl_down(v, off, 64);
  return v;
}
__device__ __forceinline__ unsigned int wredsumu(unsigned int v) {
  for (int off = 32; off; off >>= 1) v += __shfl_down(v, off, 64);
  return v;
}

__global__ void prep_kernel(const float* __restrict__ st,
                            const int* __restrict__ age,
                            const int* __restrict__ grade,
                            int* __restrict__ bcnt, int* __restrict__ cnt4,
                            unsigned short* __restrict__ ly,
                            unsigned short* __restrict__ lo,
                            unsigned short* __restrict__ hy,
                            unsigned short* __restrict__ ho, int B) {
  int i = blockIdx.x * blockDim.x + threadIdx.x;
  if (i >= B) return;
  atomicAdd(&bcnt[bucketOf(st[i])], 1);
  int a = age[i], g = grade[i];
  if (g == 0) {
    if (a < 40) ly[atomicAdd(&cnt4[0], 1)] = (unsigned short)i;
    else        lo[atomicAdd(&cnt4[1], 1)] = (unsigned short)i;
  } else if (g == 1 || g == 2) {
    if (a < 65) hy[atomicAdd(&cnt4[2], 1)] = (unsigned short)i;
    else        ho[atomicAdd(&cnt4[3], 1)] = (unsigned short)i;
  }
}

// Block 0: Cox (counting-sort by survtime bucket + suffix exp-sums).
// Blocks 1..NPAIRB: pair-rank loss over compacted young x old lists.
// Last block to finish computes the final scalar (done-counter pattern).
__global__ __launch_bounds__(TPB) void fused_kernel(
    const float* __restrict__ h3, const float* __restrict__ h1,
    const float* __restrict__ st, const float* __restrict__ cen,
    const int* __restrict__ age, const float* __restrict__ beta1p,
    const float* __restrict__ beta2p, const float* __restrict__ vars,
    Acc* __restrict__ acc, const int* __restrict__ cnt4,
    const int* __restrict__ bcnt, const unsigned short* __restrict__ ly,
    const unsigned short* __restrict__ lo,
    const unsigned short* __restrict__ hy,
    const unsigned short* __restrict__ ho, float* __restrict__ out, int B) {
  __shared__ int cursor[NBUK];          // 16 KB: bucket starts -> ends
  __shared__ unsigned short ord[NBUK];  // 8 KB: indices sorted by bucket
  __shared__ float bs3[NBUK];           // 16 KB: bucket sums -> suffix sums
  __shared__ float bs1[NBUK];           // 16 KB
  __shared__ int wsi[16];
  __shared__ float wsA[16], wsB[16];
  __shared__ double dred[32];
  __shared__ unsigned int ured[32];

  const int t = threadIdx.x;
  const int lane = t & 63, wid = t >> 6;

  if (blockIdx.x == 0) {
    // ---- phase 0: exclusive prefix of bucket counts -> cursor ----
    const int4* b4 = (const int4*)bcnt;
    int4 c = b4[t];
    int loc = c.x + c.y + c.z + c.w;
    int v = loc;
    for (int off = 1; off < 64; off <<= 1) {
      int u = __shfl_up(v, off, 64);
      if (lane >= off) v += u;
    }
    if (lane == 63) wsi[wid] = v;
    __syncthreads();
    if (t == 0) {
      int run = 0;
      for (int w = 0; w < 16; ++w) { int x = wsi[w]; wsi[w] = run; run += x; }
    }
    __syncthreads();
    int excl = v - loc + wsi[wid];
    cursor[4 * t + 0] = excl;
    cursor[4 * t + 1] = excl + c.x;
    cursor[4 * t + 2] = excl + c.x + c.y;
    cursor[4 * t + 3] = excl + c.x + c.y + c.z;
    __syncthreads();
    // ---- phase 1: scatter (counting sort). after: cursor[b] = end of b ----
    for (int i = t; i < B; i += TPB) {
      int b = bucketOf(st[i]);
      int slot = atomicAdd(&cursor[b], 1);
      ord[slot] = (unsigned short)i;
    }
    __syncthreads();
    // ---- phase 2: per-bucket exp-sums (thread owns buckets 4t..4t+3) ----
    float pv3[4], pv1[4];
    for (int k = 0; k < 4; ++k) {
      int bb = 4 * t + k;
      int lo_ = bb ? cursor[bb - 1] : 0;
      int hi_ = cursor[bb];
      float s3 = 0.f, s1 = 0.f;
      for (int m = lo_; m < hi_; ++m) {
        int j = ord[m];
        s3 += expf(h3[j]);
        s1 += expf(h1[j]);
      }
      pv3[k] = s3;
      pv1[k] = s1;
    }
    // ---- phase 3: inclusive suffix sums over buckets (both arrays) ----
    float l3_3 = pv3[3], l3_2 = pv3[2] + l3_3, l3_1 = pv3[1] + l3_2,
          l3_0 = pv3[0] + l3_1;
    float l1_3 = pv1[3], l1_2 = pv1[2] + l1_3, l1_1 = pv1[1] + l1_2,
          l1_0 = pv1[0] + l1_1;
    float vA = l3_0, vB = l1_0;
    for (int off = 1; off < 64; off <<= 1) {
      float uA = __shfl_down(vA, off, 64);
      float uB = __shfl_down(vB, off, 64);
      if (lane + off < 64) { vA += uA; vB += uB; }
    }
    if (lane == 0) { wsA[wid] = vA; wsB[wid] = vB; }
    __syncthreads();
    if (t == 0) {
      float rA = 0.f, rB = 0.f;
      for (int w = 15; w >= 0; --w) {
        float xA = wsA[w], xB = wsB[w];
        wsA[w] = rA; wsB[w] = rB;
        rA += xA; rB += xB;
      }
    }
    __syncthreads();
    float tailA = (vA - l3_0) + wsA[wid];
    float tailB = (vB - l1_0) + wsB[wid];
    bs3[4 * t + 0] = l3_0 + tailA;
    bs3[4 * t + 1] = l3_1 + tailA;
    bs3[4 * t + 2] = l3_2 + tailA;
    bs3[4 * t + 3] = l3_3 + tailA;
    bs1[4 * t + 0] = l1_0 + tailB;
    bs1[4 * t + 1] = l1_1 + tailB;
    bs1[4 * t + 2] = l1_2 + tailB;
    bs1[4 * t + 3] = l1_3 + tailB;
    __syncthreads();
    // ---- phase 4: per-element log-risk (exact ties within own bucket) ----
    double a3 = 0.0, a1 = 0.0;
    for (int i = t; i < B; i += TPB) {
      float ci = cen[i];
      if (ci == 0.f) continue;
      float si = st[i];
      int b = bucketOf(si);
      float T3 = (b + 1 < NBUK) ? bs3[b + 1] : 0.f;
      float T1 = (b + 1 < NBUK) ? bs1[b + 1] : 0.f;
      int lo_ = b ? cursor[b - 1] : 0;
      int hi_ = cursor[b];
      for (int m = lo_; m < hi_; ++m) {
        int j = ord[m];
        if (st[j] >= si) { T3 += expf(h3[j]); T1 += expf(h1[j]); }
      }
      a3 += (double)((h3[i] - logf(T3)) * ci);
      a1 += (double)((h1[i] - logf(T1)) * ci);
    }
    double w3 = wredsum(a3), w1 = wredsum(a1);
    if (lane == 0) { dred[wid] = w3; dred[16 + wid] = w1; }
    __syncthreads();
    if (t == 0) {
      double S3 = 0, S1 = 0;
      for (int w = 0; w < 16; ++w) { S3 += dred[w]; S1 += dred[16 + w]; }
      atomicAdd(&acc->sum3, S3);
      atomicAdd(&acc->sum1, S1);
    }
  } else {
    // ---- pair-rank loss over compacted cross lists ----
    int nly = cnt4[0], nlo = cnt4[1], nhy = cnt4[2], nho = cnt4[3];
    int totL = nly * nlo;
    int tot = totL + nhy * nho;
    float b1 = beta1p[0], b2 = beta2p[0];
    int stride = (gridDim.x - 1) * TPB;
    double tl = 0.0, th = 0.0;
    unsigned int nl = 0, nh = 0;
    for (int idx = (blockIdx.x - 1) * TPB + t; idx < tot; idx += stride) {
      int i, j;
      float beta;
      bool isL = idx < totL;
      if (isL) {
        i = ly[idx / nlo];
        j = lo[idx % nlo];
        beta = b1;
      } else {
        int r = idx - totL;
        i = hy[r / nho];
        j = ho[r % nho];
        beta = b2;
      }
      if (i < j) {  // triu constraint on original indices
        float d = (riskOf(age[j]) - riskOf(age[i])) * 0.125f;
        float alpha = d / (1.f + expf(-beta * d));  // swish(d, beta)
        float x = alpha * (h3[i] - h3[j]);
        float term = fmaxf(x, 0.f) + log1pf(expf(-fabsf(x)));  // softplus
        if (isL) { tl += (double)term; nl++; }
        else     { th += (double)term; nh++; }
      }
    }
    double wl = wredsum(tl), wh = wredsum(th);
    unsigned int ul = wredsumu(nl), uh = wredsumu(nh);
    if (lane == 0) {
      dred[wid] = wl; dred[16 + wid] = wh;
      ured[wid] = ul; ured[16 + wid] = uh;
    }
    __syncthreads();
    if (t == 0) {
      double SL = 0, SH = 0;
      unsigned long long NL = 0, NH = 0;
      for (int w = 0; w < 16; ++w) {
        SL += dred[w]; SH += dred[16 + w];
        NL += ured[w]; NH += ured[16 + w];
      }
      if (SL != 0.0) atomicAdd(&acc->tot_l, SL);
      if (SH != 0.0) atomicAdd(&acc->tot_h, SH);
      if (NL) atomicAdd(&acc->n_l, NL);
      if (NH) atomicAdd(&acc->n_h, NH);
    }
  }

  // ---- arrival; last block finalizes ----
  __syncthreads();
  if (t == 0) {
    __threadfence();
    unsigned int old = atomicAdd(&acc->done, 1u);
    if (old == gridDim.x - 1) {
      __threadfence();
      double s3 = atomicAdd(&acc->sum3, 0.0);
      double s1 = atomicAdd(&acc->sum1, 0.0);
      double tl_ = atomicAdd(&acc->tot_l, 0.0);
      double th_ = atomicAdd(&acc->tot_h, 0.0);
      unsigned long long nl_ = atomicAdd(&acc->n_l, 0ull);
      unsigned long long nh_ = atomicAdd(&acc->n_h, 0ull);
      float loss3d = (float)(-s3 / (double)B);
      float loss1d = (float)(-s1 / (double)B);
      float lgg = nl_ ? (float)(tl_ / (double)nl_) : 0.f;
      float hgg = nh_ ? (float)(th_ / (double)nh_) : 0.f;
      float losscli = lgg + hgg;
      float v0 = vars[0], v2 = vars[2], v3 = vars[3];
      float r = 0.5f * loss3d / (v0 * v0) + logf(v0);
      r += 0.5f * loss1d / (v2 * v2) + logf(v2);
      r += 0.5f * losscli / (v3 * v3) + logf(v3);
      out[0] = r;
    }
  }
}

extern "C" void kernel_launch(void* const* d_in, const int* in_sizes, int n_in,
                              void* d_out, int out_size, void* d_ws,
                              size_t ws_size, hipStream_t stream) {
  const float* h3 = (const float*)d_in[0];
  const float* h1 = (const float*)d_in[1];
  const float* st = (const float*)d_in[2];
  const float* cen = (const float*)d_in[3];
  const float* vars = (const float*)d_in[4];
  const float* beta1 = (const float*)d_in[5];
  const float* beta2 = (const float*)d_in[6];
  const int* age = (const int*)d_in[7];
  const int* grade = (const int*)d_in[8];
  const int B = in_sizes[0];

  char* ws = (char*)d_ws;
  Acc* acc = (Acc*)ws;
  int* cnt4 = (int*)(ws + 64);
  int* bcnt = (int*)(ws + 128);
  unsigned short* ly = (unsigned short*)(ws + 16512);
  unsigned short* lo = (unsigned short*)(ws + 24704);
  unsigned short* hy = (unsigned short*)(ws + 32896);
  unsigned short* ho = (unsigned short*)(ws + 41088);
  float* out = (float*)d_out;

  hipMemsetAsync(d_ws, 0, 16512, stream);
  prep_kernel<<<(B + 255) / 256, 256, 0, stream>>>(st, age, grade, bcnt, cnt4,
                                                   ly, lo, hy, ho, B);
  fused_kernel<<<NPAIRB + 1, TPB, 0, stream>>>(h3, h1, st, cen, age, beta1,
                                               beta2, vars, acc, cnt4, bcnt,
                                               ly, lo, hy, ho, out, B);
}

// Round 3
// 120.461 us; speedup vs baseline: 2.0199x; 1.2104x over previous
//
#include <hip/hip_runtime.h>
#include <math.h>

#define TPB 1024
#define NBUK 4096
#define NPAIR 32
#define NSLOT (2 + NPAIR)  // blocks 0,1 = Cox(h3), Cox(h1); 2..33 = pair

struct Slot {
  double a, b;           // cox: (sum3,0)/(0,sum1); pair: (tot_l, tot_h)
  unsigned int c, d;     // pair: (n_l, n_h)
  double pad;
};

__device__ const float RISK[9] = {1.0f, 1.0f, 0.91f, 1.12f, 1.71f,
                                  2.41f, 3.27f, 5.18f, 8.44f};

__device__ __forceinline__ int bucketOf(float s) {
  int b = (int)(s * 4096.0f);  // power-of-two scale: exact, monotone
  return b < 0 ? 0 : (b > 4095 ? 4095 : b);
}
__device__ __forceinline__ int decadeOf(int a) {
  int d = a / 10;
  return d > 8 ? 8 : (d < 0 ? 0 : d);
}
__device__ __forceinline__ double wredsumd(double v) {
  for (int off = 32; off; off >>= 1) v += __shfl_down(v, off, 64);
  return v;
}
__device__ __forceinline__ unsigned int wredsumu(unsigned int v) {
  for (int off = 32; off; off >>= 1) v += __shfl_down(v, off, 64);
  return v;
}

__global__ __launch_bounds__(TPB) void fused_kernel(
    const float* __restrict__ h3, const float* __restrict__ h1,
    const float* __restrict__ st, const float* __restrict__ cen,
    const int* __restrict__ age, const int* __restrict__ grade,
    const float* __restrict__ b1p, const float* __restrict__ b2p,
    Slot* __restrict__ slots, int B) {
  __shared__ int smem_i[10240];  // 40 KB, overlaid per branch
  __shared__ int wsi[16];
  __shared__ float wsA[16];
  __shared__ double dred[32];
  __shared__ unsigned int ured[32];

  const int t = threadIdx.x, lane = t & 63, wid = t >> 6;
  const int bid = blockIdx.x;

  if (bid < 2) {
    // ================= Cox partial-likelihood (one hazard array) ==========
    const float* h = (bid == 0) ? h3 : h1;
    int* cursor = smem_i;                                     // [4096] 16 KB
    unsigned short* ord = (unsigned short*)(smem_i + 4096);   // [4096]  8 KB
    float* bs = (float*)(smem_i + 6144);                      // [4096] 16 KB

    for (int k = t; k < NBUK; k += TPB) cursor[k] = 0;
    __syncthreads();
    int myb[4];
    for (int k = 0; k < 4; ++k) {
      int i = t + k * TPB;
      int b = (i < B) ? bucketOf(st[i]) : -1;
      myb[k] = b;
      if (b >= 0) atomicAdd(&cursor[b], 1);
    }
    __syncthreads();
    // exclusive prefix of bucket counts -> bucket starts
    int c0 = cursor[4 * t], c1 = cursor[4 * t + 1], c2 = cursor[4 * t + 2],
        c3 = cursor[4 * t + 3];
    int loc = c0 + c1 + c2 + c3;
    int v = loc;
    for (int off = 1; off < 64; off <<= 1) {
      int u = __shfl_up(v, off, 64);
      if (lane >= off) v += u;
    }
    if (lane == 63) wsi[wid] = v;
    __syncthreads();
    if (t == 0) {
      int run = 0;
      for (int w = 0; w < 16; ++w) { int x = wsi[w]; wsi[w] = run; run += x; }
    }
    __syncthreads();
    int excl = v - loc + wsi[wid];
    cursor[4 * t + 0] = excl;
    cursor[4 * t + 1] = excl + c0;
    cursor[4 * t + 2] = excl + c0 + c1;
    cursor[4 * t + 3] = excl + c0 + c1 + c2;
    __syncthreads();
    // counting-sort scatter; after this cursor[b] = end of bucket b
    for (int k = 0; k < 4; ++k)
      if (myb[k] >= 0) {
        int slot = atomicAdd(&cursor[myb[k]], 1);
        ord[slot] = (unsigned short)(t + k * TPB);
      }
    __syncthreads();
    // per-bucket exp sums (thread owns buckets 4t..4t+3)
    float pv[4];
    for (int k = 0; k < 4; ++k) {
      int bb = 4 * t + k;
      int lo_ = bb ? cursor[bb - 1] : 0;
      int hi_ = cursor[bb];
      float s = 0.f;
      for (int m = lo_; m < hi_; ++m) s += expf(h[ord[m]]);
      pv[k] = s;
    }
    // inclusive suffix sum over 4096 buckets
    float l3 = pv[3], l2 = pv[2] + l3, l1 = pv[1] + l2, l0 = pv[0] + l1;
    float vA = l0;
    for (int off = 1; off < 64; off <<= 1) {
      float u = __shfl_down(vA, off, 64);
      if (lane + off < 64) vA += u;
    }
    if (lane == 0) wsA[wid] = vA;
    __syncthreads();
    if (t == 0) {
      float r = 0.f;
      for (int w = 15; w >= 0; --w) { float x = wsA[w]; wsA[w] = r; r += x; }
    }
    __syncthreads();
    float tail = (vA - l0) + wsA[wid];
    bs[4 * t + 0] = l0 + tail;
    bs[4 * t + 1] = l1 + tail;
    bs[4 * t + 2] = l2 + tail;
    bs[4 * t + 3] = l3 + tail;
    __syncthreads();
    // per-element log-risk (exact tie handling within own bucket)
    double a = 0.0;
    for (int k = 0; k < 4; ++k) {
      int i = t + k * TPB;
      if (i >= B) break;
      float ci = cen[i];
      if (ci == 0.f) continue;
      float si = st[i];
      int b = myb[k];
      float T = (b + 1 < NBUK) ? bs[b + 1] : 0.f;
      int lo_ = b ? cursor[b - 1] : 0;
      int hi_ = cursor[b];
      for (int m = lo_; m < hi_; ++m) {
        int j = ord[m];
        if (st[j] >= si) T += expf(h[j]);
      }
      a += (double)((h[i] - logf(T)) * ci);
    }
    double w = wredsumd(a);
    if (lane == 0) dred[wid] = w;
    __syncthreads();
    if (t == 0) {
      double S = 0;
      for (int w2 = 0; w2 < 16; ++w2) S += dred[w2];
      slots[bid].a = (bid == 0) ? S : 0.0;
      slots[bid].b = (bid == 0) ? 0.0 : S;
      slots[bid].c = 0u;
      slots[bid].d = 0u;
    }
  } else {
    // ================= pair-rank losses (LDS-resident lists) ==============
    uint2* pool = (uint2*)smem_i;            // [4096] 32 KB packed records
    float* aL = (float*)(smem_i + 8192);     // [81] alpha LUT beta1
    float* aH = aL + 81;                     // [81] alpha LUT beta2
    int* cnts = (int*)(aH + 81);             // [8]: counts + cursors
    const float b1 = b1p[0], b2 = b2p[0];

    if (t < 162) {
      int q = (t < 81) ? t : t - 81;
      float beta = (t < 81) ? b1 : b2;
      int dy = q / 9, dq = q - 9 * dy;
      float d = (RISK[dq] - RISK[dy]) * 0.125f;
      float al = d / (1.f + expf(-beta * d));  // swish(d, beta)
      if (t < 81) aL[q] = al; else aH[q] = al;
    }
    if (t < 8) cnts[t] = 0;
    __syncthreads();
    // classify + count (cat 0:lgg-young 1:lgg-old 2:hgg-young 3:hgg-old)
    int cat[4], dec[4];
    for (int k = 0; k < 4; ++k) {
      int i = t + k * TPB;
      int c = -1, dc = 0;
      if (i < B) {
        int a_ = age[i], g = grade[i];
        dc = decadeOf(a_);
        if (g == 0) c = (a_ < 40) ? 0 : 1;
        else if (g == 1 || g == 2) c = (a_ < 65) ? 2 : 3;
      }
      cat[k] = c;
      dec[k] = dc;
      if (c >= 0) atomicAdd(&cnts[c], 1);
    }
    __syncthreads();
    const int nly = cnts[0], nlo = cnts[1], nhy = cnts[2], nho = cnts[3];
    if (t == 0) {
      cnts[4] = 0;
      cnts[5] = nly;
      cnts[6] = nly + nlo;
      cnts[7] = nly + nlo + nhy;
    }
    __syncthreads();
    for (int k = 0; k < 4; ++k) {
      int c = cat[k];
      if (c >= 0) {
        int i = t + k * TPB;
        int slot = atomicAdd(&cnts[4 + c], 1);
        pool[slot] =
            make_uint2(__float_as_uint(h3[i]), (unsigned)((i << 4) | dec[k]));
      }
    }
    __syncthreads();
    const int bLO = nly, bHY = nly + nlo, bHO = nly + nlo + nhy;

    double tl = 0.0, th = 0.0;
    unsigned int nl = 0, nh = 0;
    const int pb = bid - 2;
    // LGG: youngs strided across blocks, olds strided across threads
    for (int yi = pb; yi < nly; yi += NPAIR) {
      uint2 yr = pool[yi];
      float h3y = __uint_as_float(yr.x);
      int iy = (int)(yr.y >> 4);
      const float* aRow = &aL[(yr.y & 15u) * 9];
      for (int oi = t; oi < nlo; oi += TPB) {
        uint2 orc = pool[bLO + oi];
        if ((int)(orc.y >> 4) > iy) {
          float x = aRow[orc.y & 15u] * (h3y - __uint_as_float(orc.x));
          tl += (double)(fmaxf(x, 0.f) + log1pf(expf(-fabsf(x))));
          nl++;
        }
      }
    }
    // HGG
    for (int yi = pb; yi < nhy; yi += NPAIR) {
      uint2 yr = pool[bHY + yi];
      float h3y = __uint_as_float(yr.x);
      int iy = (int)(yr.y >> 4);
      const float* aRow = &aH[(yr.y & 15u) * 9];
      for (int oi = t; oi < nho; oi += TPB) {
        uint2 orc = pool[bHO + oi];
        if ((int)(orc.y >> 4) > iy) {
          float x = aRow[orc.y & 15u] * (h3y - __uint_as_float(orc.x));
          th += (double)(fmaxf(x, 0.f) + log1pf(expf(-fabsf(x))));
          nh++;
        }
      }
    }
    double wl = wredsumd(tl), wh = wredsumd(th);
    unsigned int ul = wredsumu(nl), uh = wredsumu(nh);
    if (lane == 0) {
      dred[wid] = wl;
      dred[16 + wid] = wh;
      ured[wid] = ul;
      ured[16 + wid] = uh;
    }
    __syncthreads();
    if (t == 0) {
      double SL = 0, SH = 0;
      unsigned int NL = 0, NH = 0;
      for (int w = 0; w < 16; ++w) {
        SL += dred[w];
        SH += dred[16 + w];
        NL += ured[w];
        NH += ured[16 + w];
      }
      slots[bid].a = SL;
      slots[bid].b = SH;
      slots[bid].c = NL;
      slots[bid].d = NH;
    }
  }
}

__global__ void final_kernel(const Slot* __restrict__ slots,
                             const float* __restrict__ vars,
                             float* __restrict__ out, int B) {
  const int lane = threadIdx.x & 63;
  double s3 = 0, s1 = 0, tl = 0, th = 0;
  unsigned long long nl = 0, nh = 0;
  if (lane < NSLOT) {
    Slot s = slots[lane];
    if (lane < 2) {
      s3 = s.a;
      s1 = s.b;
    } else {
      tl = s.a;
      th = s.b;
      nl = s.c;
      nh = s.d;
    }
  }
  for (int off = 32; off; off >>= 1) {
    s3 += __shfl_down(s3, off, 64);
    s1 += __shfl_down(s1, off, 64);
    tl += __shfl_down(tl, off, 64);
    th += __shfl_down(th, off, 64);
    nl += __shfl_down(nl, off, 64);
    nh += __shfl_down(nh, off, 64);
  }
  if (threadIdx.x == 0) {
    float loss3d = (float)(-s3 / (double)B);
    float loss1d = (float)(-s1 / (double)B);
    float lgg = nl ? (float)(tl / (double)nl) : 0.f;
    float hgg = nh ? (float)(th / (double)nh) : 0.f;
    float losscli = lgg + hgg;
    float v0 = vars[0], v2 = vars[2], v3 = vars[3];
    float r = 0.5f * loss3d / (v0 * v0) + logf(v0);
    r += 0.5f * loss1d / (v2 * v2) + logf(v2);
    r += 0.5f * losscli / (v3 * v3) + logf(v3);
    out[0] = r;
  }
}

extern "C" void kernel_launch(void* const* d_in, const int* in_sizes, int n_in,
                              void* d_out, int out_size, void* d_ws,
                              size_t ws_size, hipStream_t stream) {
  const float* h3 = (const float*)d_in[0];
  const float* h1 = (const float*)d_in[1];
  const float* st = (const float*)d_in[2];
  const float* cen = (const float*)d_in[3];
  const float* vars = (const float*)d_in[4];
  const float* beta1 = (const float*)d_in[5];
  const float* beta2 = (const float*)d_in[6];
  const int* age = (const int*)d_in[7];
  const int* grade = (const int*)d_in[8];
  const int B = in_sizes[0];

  Slot* slots = (Slot*)d_ws;  // every slot written unconditionally: no init
  float* out = (float*)d_out;

  fused_kernel<<<NSLOT, TPB, 0, stream>>>(h3, h1, st, cen, age, grade, beta1,
                                          beta2, slots, B);
  final_kernel<<<1, 64, 0, stream>>>(slots, vars, out, B);
}

// Round 4
// 118.479 us; speedup vs baseline: 2.0537x; 1.0167x over previous
//
#include <hip/hip_runtime.h>
#include <math.h>

#define TPB 1024
#define NBUK 4096
#define NPAIR 32
#define NSLOT (2 + NPAIR)  // blocks 0,1 = Cox(h3), Cox(h1); 2..33 = pair
#define FLAG_MAGIC 0x13579BDFu

struct Slot {
  double a, b;        // cox: (sum3,0)/(0,sum1); pair: (tot_l, tot_h)
  unsigned int c, d;  // pair: (n_l, n_h)
  unsigned int flag;  // FLAG_MAGIC when slot valid (ws poison 0xAA != magic)
  unsigned int pad;
};

__device__ const float RISK[9] = {1.0f, 1.0f, 0.91f, 1.12f, 1.71f,
                                  2.41f, 3.27f, 5.18f, 8.44f};

__device__ __forceinline__ int bucketOf(float s) {
  int b = (int)(s * 4096.0f);  // power-of-two scale: exact, monotone
  return b < 0 ? 0 : (b > 4095 ? 4095 : b);
}
__device__ __forceinline__ int decadeOf(int a) {
  int d = a / 10;
  return d > 8 ? 8 : (d < 0 ? 0 : d);
}
__device__ __forceinline__ double wredsumd(double v) {
  for (int off = 32; off; off >>= 1) v += __shfl_down(v, off, 64);
  return v;
}
__device__ __forceinline__ unsigned int wredsumu(unsigned int v) {
  for (int off = 32; off; off >>= 1) v += __shfl_down(v, off, 64);
  return v;
}

__global__ __launch_bounds__(TPB) void fused_kernel(
    const float* __restrict__ h3, const float* __restrict__ h1,
    const float* __restrict__ st, const float* __restrict__ cen,
    const int* __restrict__ age, const int* __restrict__ grade,
    const float* __restrict__ b1p, const float* __restrict__ b2p,
    const float* __restrict__ vars, Slot* __restrict__ slots,
    float* __restrict__ out, int B) {
  __shared__ int smem_i[18432];  // 72 KB, overlaid per branch
  __shared__ int wsi[16];
  __shared__ float wsA[16];
  __shared__ double dred[32];
  __shared__ unsigned int ured[32];

  const int t = threadIdx.x, lane = t & 63, wid = t >> 6;
  const int bid = blockIdx.x;

  if (bid < 2) {
    // ================= Cox partial-likelihood (one hazard array) ==========
    const float* h = (bid == 0) ? h3 : h1;
    int* cursor = smem_i;                                    // [4096] 16 KB
    unsigned short* ord = (unsigned short*)(smem_i + 4096);  // [4096]  8 KB
    float* bs = (float*)(smem_i + 6144);                     // [4096] 16 KB
    float* h_lds = (float*)(smem_i + 10240);                 // [4096] 16 KB
    float* st_lds = (float*)(smem_i + 14336);                // [4096] 16 KB

    // stage h/st coalesced + zero cursor (one pass, one barrier)
    for (int k = 0; k < 4; ++k) {
      int i = t + k * TPB;
      cursor[i] = 0;
      if (i < B) {
        h_lds[i] = h[i];
        st_lds[i] = st[i];
      } else {
        h_lds[i] = 0.f;
        st_lds[i] = 2.f;  // > any real st: never counted at-risk
      }
    }
    __syncthreads();
    int myb[4];
    for (int k = 0; k < 4; ++k) {
      int i = t + k * TPB;
      int b = (i < B) ? bucketOf(st_lds[i]) : -1;
      myb[k] = b;
      if (b >= 0) atomicAdd(&cursor[b], 1);
    }
    __syncthreads();
    // exclusive prefix of bucket counts -> bucket starts
    int c0 = cursor[4 * t], c1 = cursor[4 * t + 1], c2 = cursor[4 * t + 2],
        c3 = cursor[4 * t + 3];
    int loc = c0 + c1 + c2 + c3;
    int v = loc;
    for (int off = 1; off < 64; off <<= 1) {
      int u = __shfl_up(v, off, 64);
      if (lane >= off) v += u;
    }
    if (lane == 63) wsi[wid] = v;
    __syncthreads();
    if (t == 0) {
      int run = 0;
      for (int w = 0; w < 16; ++w) {
        int x = wsi[w];
        wsi[w] = run;
        run += x;
      }
    }
    __syncthreads();
    int excl = v - loc + wsi[wid];
    cursor[4 * t + 0] = excl;
    cursor[4 * t + 1] = excl + c0;
    cursor[4 * t + 2] = excl + c0 + c1;
    cursor[4 * t + 3] = excl + c0 + c1 + c2;
    __syncthreads();
    // counting-sort scatter; after this cursor[b] = end of bucket b
    for (int k = 0; k < 4; ++k)
      if (myb[k] >= 0) {
        int slot = atomicAdd(&cursor[myb[k]], 1);
        ord[slot] = (unsigned short)(t + k * TPB);
      }
    __syncthreads();
    // per-bucket exp sums (thread owns buckets 4t..4t+3), all LDS
    float pv[4];
    for (int k = 0; k < 4; ++k) {
      int bb = 4 * t + k;
      int lo_ = bb ? cursor[bb - 1] : 0;
      int hi_ = cursor[bb];
      float s = 0.f;
      for (int m = lo_; m < hi_; ++m) s += expf(h_lds[ord[m]]);
      pv[k] = s;
    }
    // inclusive suffix sum over 4096 buckets
    float l3 = pv[3], l2 = pv[2] + l3, l1 = pv[1] + l2, l0 = pv[0] + l1;
    float vA = l0;
    for (int off = 1; off < 64; off <<= 1) {
      float u = __shfl_down(vA, off, 64);
      if (lane + off < 64) vA += u;
    }
    if (lane == 0) wsA[wid] = vA;
    __syncthreads();
    if (t == 0) {
      float r = 0.f;
      for (int w = 15; w >= 0; --w) {
        float x = wsA[w];
        wsA[w] = r;
        r += x;
      }
    }
    __syncthreads();
    float tail = (vA - l0) + wsA[wid];
    bs[4 * t + 0] = l0 + tail;
    bs[4 * t + 1] = l1 + tail;
    bs[4 * t + 2] = l2 + tail;
    bs[4 * t + 3] = l3 + tail;
    __syncthreads();
    // per-element log-risk (exact tie handling within own bucket)
    double a = 0.0;
    for (int k = 0; k < 4; ++k) {
      int i = t + k * TPB;
      if (i >= B) break;
      float ci = cen[i];
      if (ci == 0.f) continue;
      float si = st_lds[i];
      int b = myb[k];
      float T = (b + 1 < NBUK) ? bs[b + 1] : 0.f;
      int lo_ = b ? cursor[b - 1] : 0;
      int hi_ = cursor[b];
      for (int m = lo_; m < hi_; ++m) {
        int j = ord[m];
        if (st_lds[j] >= si) T += expf(h_lds[j]);
      }
      a += (double)((h_lds[i] - logf(T)) * ci);
    }
    double w = wredsumd(a);
    if (lane == 0) dred[wid] = w;
    __syncthreads();
    if (t == 0) {
      double S = 0;
      for (int w2 = 0; w2 < 16; ++w2) S += dred[w2];
      slots[bid].a = (bid == 0) ? S : 0.0;
      slots[bid].b = (bid == 0) ? 0.0 : S;
      slots[bid].c = 0u;
      slots[bid].d = 0u;
      __hip_atomic_store(&slots[bid].flag, FLAG_MAGIC, __ATOMIC_RELEASE,
                         __HIP_MEMORY_SCOPE_AGENT);
    }
  } else {
    // ================= pair-rank losses (LDS-resident lists) ==============
    uint2* pool = (uint2*)smem_i;         // [4096] 32 KB packed records
    float* aL = (float*)(smem_i + 8192);  // [81] alpha LUT beta1
    float* aH = aL + 81;                  // [81] alpha LUT beta2
    int* cnts = (int*)(aH + 81);          // [8]: counts + cursors
    const float b1 = b1p[0], b2 = b2p[0];

    if (t < 162) {
      int q = (t < 81) ? t : t - 81;
      float beta = (t < 81) ? b1 : b2;
      int dy = q / 9, dq = q - 9 * dy;
      float d = (RISK[dq] - RISK[dy]) * 0.125f;
      float al = d / (1.f + expf(-beta * d));  // swish(d, beta)
      if (t < 81) aL[q] = al;
      else aH[q] = al;
    }
    if (t < 8) cnts[t] = 0;
    __syncthreads();
    // classify + count (cat 0:lgg-young 1:lgg-old 2:hgg-young 3:hgg-old)
    int cat[4], dec[4];
    for (int k = 0; k < 4; ++k) {
      int i = t + k * TPB;
      int c = -1, dc = 0;
      if (i < B) {
        int a_ = age[i], g = grade[i];
        dc = decadeOf(a_);
        if (g == 0) c = (a_ < 40) ? 0 : 1;
        else if (g == 1 || g == 2) c = (a_ < 65) ? 2 : 3;
      }
      cat[k] = c;
      dec[k] = dc;
      if (c >= 0) atomicAdd(&cnts[c], 1);
    }
    __syncthreads();
    const int nly = cnts[0], nlo = cnts[1], nhy = cnts[2], nho = cnts[3];
    if (t == 0) {
      cnts[4] = 0;
      cnts[5] = nly;
      cnts[6] = nly + nlo;
      cnts[7] = nly + nlo + nhy;
    }
    __syncthreads();
    for (int k = 0; k < 4; ++k) {
      int c = cat[k];
      if (c >= 0) {
        int i = t + k * TPB;
        int slot = atomicAdd(&cnts[4 + c], 1);
        pool[slot] =
            make_uint2(__float_as_uint(h3[i]), (unsigned)((i << 4) | dec[k]));
      }
    }
    __syncthreads();
    const int bLO = nly, bHY = nly + nlo, bHO = nly + nlo + nhy;

    double tl = 0.0, th = 0.0;
    unsigned int nl = 0, nh = 0;
    const int pb = bid - 2;
    // LGG: youngs strided across blocks, olds strided across threads
    for (int yi = pb; yi < nly; yi += NPAIR) {
      uint2 yr = pool[yi];
      float h3y = __uint_as_float(yr.x);
      int iy = (int)(yr.y >> 4);
      const float* aRow = &aL[(yr.y & 15u) * 9];
      for (int oi = t; oi < nlo; oi += TPB) {
        uint2 orc = pool[bLO + oi];
        if ((int)(orc.y >> 4) > iy) {
          float x = aRow[orc.y & 15u] * (h3y - __uint_as_float(orc.x));
          tl += (double)(fmaxf(x, 0.f) + log1pf(expf(-fabsf(x))));
          nl++;
        }
      }
    }
    // HGG
    for (int yi = pb; yi < nhy; yi += NPAIR) {
      uint2 yr = pool[bHY + yi];
      float h3y = __uint_as_float(yr.x);
      int iy = (int)(yr.y >> 4);
      const float* aRow = &aH[(yr.y & 15u) * 9];
      for (int oi = t; oi < nho; oi += TPB) {
        uint2 orc = pool[bHO + oi];
        if ((int)(orc.y >> 4) > iy) {
          float x = aRow[orc.y & 15u] * (h3y - __uint_as_float(orc.x));
          th += (double)(fmaxf(x, 0.f) + log1pf(expf(-fabsf(x))));
          nh++;
        }
      }
    }
    double wl = wredsumd(tl), wh = wredsumd(th);
    unsigned int ul = wredsumu(nl), uh = wredsumu(nh);
    if (lane == 0) {
      dred[wid] = wl;
      dred[16 + wid] = wh;
      ured[wid] = ul;
      ured[16 + wid] = uh;
    }
    __syncthreads();
    if (t == 0) {
      double SL = 0, SH = 0;
      unsigned int NL = 0, NH = 0;
      for (int w = 0; w < 16; ++w) {
        SL += dred[w];
        SH += dred[16 + w];
        NL += ured[w];
        NH += ured[16 + w];
      }
      slots[bid].a = SL;
      slots[bid].b = SH;
      slots[bid].c = NL;
      slots[bid].d = NH;
      __hip_atomic_store(&slots[bid].flag, FLAG_MAGIC, __ATOMIC_RELEASE,
                         __HIP_MEMORY_SCOPE_AGENT);
    }
  }

  // ============ block 0, wave 0: spin on all slots, finalize ============
  // All 34 blocks are co-resident (34 << 256 CUs): spin cannot deadlock.
  if (bid == 0 && wid == 0) {
    double s3 = 0, s1 = 0, tl = 0, th = 0;
    unsigned long long nl = 0, nh = 0;
    if (lane < NSLOT) {
      while (__hip_atomic_load(&slots[lane].flag, __ATOMIC_ACQUIRE,
                               __HIP_MEMORY_SCOPE_AGENT) != FLAG_MAGIC)
        __builtin_amdgcn_s_sleep(8);
      double a = slots[lane].a;
      double b = slots[lane].b;
      unsigned int c = slots[lane].c;
      unsigned int d = slots[lane].d;
      if (lane < 2) {
        s3 = a;
        s1 = b;
      } else {
        tl = a;
        th = b;
        nl = c;
        nh = d;
      }
    }
    for (int off = 32; off; off >>= 1) {
      s3 += __shfl_down(s3, off, 64);
      s1 += __shfl_down(s1, off, 64);
      tl += __shfl_down(tl, off, 64);
      th += __shfl_down(th, off, 64);
      nl += __shfl_down(nl, off, 64);
      nh += __shfl_down(nh, off, 64);
    }
    if (lane == 0) {
      float loss3d = (float)(-s3 / (double)B);
      float loss1d = (float)(-s1 / (double)B);
      float lgg = nl ? (float)(tl / (double)nl) : 0.f;
      float hgg = nh ? (float)(th / (double)nh) : 0.f;
      float losscli = lgg + hgg;
      float v0 = vars[0], v2 = vars[2], v3 = vars[3];
      float r = 0.5f * loss3d / (v0 * v0) + logf(v0);
      r += 0.5f * loss1d / (v2 * v2) + logf(v2);
      r += 0.5f * losscli / (v3 * v3) + logf(v3);
      out[0] = r;
    }
  }
}

extern "C" void kernel_launch(void* const* d_in, const int* in_sizes, int n_in,
                              void* d_out, int out_size, void* d_ws,
                              size_t ws_size, hipStream_t stream) {
  const float* h3 = (const float*)d_in[0];
  const float* h1 = (const float*)d_in[1];
  const float* st = (const float*)d_in[2];
  const float* cen = (const float*)d_in[3];
  const float* vars = (const float*)d_in[4];
  const float* beta1 = (const float*)d_in[5];
  const float* beta2 = (const float*)d_in[6];
  const int* age = (const int*)d_in[7];
  const int* grade = (const int*)d_in[8];
  const int B = in_sizes[0];

  Slot* slots = (Slot*)d_ws;  // every slot written unconditionally: no init
  float* out = (float*)d_out;

  fused_kernel<<<NSLOT, TPB, 0, stream>>>(h3, h1, st, cen, age, grade, beta1,
                                          beta2, vars, slots, out, B);
}

// Round 5
// 82.196 us; speedup vs baseline: 2.9603x; 1.4414x over previous
//
#include <hip/hip_runtime.h>
#include <math.h>

#define TPB 1024
#define NBUK 4096
#define NPL 20                      // LGG pair blocks
#define NPH 74                      // HGG pair blocks
#define NSLOT (2 + NPL + NPH)       // 96: 0,1 Cox; 2..21 LGG; 22..95 HGG
#define FLAG_MAGIC 0x13579BDFu

struct Slot {
  double a, b;        // cox: (sum3,0)/(0,sum1); pair: (tot, 0)
  unsigned int c, d;  // pair: (n, 0)
  unsigned int flag;  // FLAG_MAGIC when valid (ws poison 0xAA != magic)
  unsigned int pad;
};

__device__ const float RISK[9] = {1.0f, 1.0f, 0.91f, 1.12f, 1.71f,
                                  2.41f, 3.27f, 5.18f, 8.44f};

__device__ __forceinline__ int bucketOf(float s) {
  int b = (int)(s * 4096.0f);  // power-of-two scale: exact, monotone
  return b < 0 ? 0 : (b > 4095 ? 4095 : b);
}
__device__ __forceinline__ int decadeOf(int a) {
  int d = a / 10;
  return d > 8 ? 8 : (d < 0 ? 0 : d);
}
__device__ __forceinline__ double wredsumd(double v) {
  for (int off = 32; off; off >>= 1) v += __shfl_down(v, off, 64);
  return v;
}
__device__ __forceinline__ unsigned int wredsumu(unsigned int v) {
  for (int off = 32; off; off >>= 1) v += __shfl_down(v, off, 64);
  return v;
}

__global__ __launch_bounds__(TPB) void fused_kernel(
    const float* __restrict__ h3, const float* __restrict__ h1,
    const float* __restrict__ st, const float* __restrict__ cen,
    const int* __restrict__ age, const int* __restrict__ grade,
    const float* __restrict__ b1p, const float* __restrict__ b2p,
    const float* __restrict__ vars, Slot* __restrict__ slots,
    float* __restrict__ out, int B) {
  __shared__ int smem_i[18432];  // 72 KB, overlaid per branch
  __shared__ int wsi[16];
  __shared__ float wsA[16];
  __shared__ double dred[32];
  __shared__ unsigned int ured[16];

  const int t = threadIdx.x, lane = t & 63, wid = t >> 6;
  const int bid = blockIdx.x;

  if (bid < 2) {
    // ================= Cox partial-likelihood (one hazard array) ==========
    const float* h = (bid == 0) ? h3 : h1;
    int* cursor = smem_i;                                    // [4096] 16 KB
    unsigned short* ord = (unsigned short*)(smem_i + 4096);  // [4096]  8 KB
    float* bs = (float*)(smem_i + 6144);                     // [4096] 16 KB
    float* h_lds = (float*)(smem_i + 10240);                 // [4096] 16 KB
    float* st_lds = (float*)(smem_i + 14336);                // [4096] 16 KB

    // stage h/st (vectorized) + zero cursor (one pass, one barrier)
    float s4[4], hv4[4];
    ((int4*)cursor)[t] = make_int4(0, 0, 0, 0);
    if (4 * t + 3 < B) {
      float4 hv = ((const float4*)h)[t];
      float4 sv = ((const float4*)st)[t];
      ((float4*)h_lds)[t] = hv;
      ((float4*)st_lds)[t] = sv;
      hv4[0] = hv.x; hv4[1] = hv.y; hv4[2] = hv.z; hv4[3] = hv.w;
      s4[0] = sv.x; s4[1] = sv.y; s4[2] = sv.z; s4[3] = sv.w;
    } else {
      for (int k = 0; k < 4; ++k) {
        int i = 4 * t + k;
        float hh = (i < B) ? h[i] : 0.f;
        float ss = (i < B) ? st[i] : 2.f;  // sentinel > any st
        h_lds[i] = hh;
        st_lds[i] = ss;
        hv4[k] = hh;
        s4[k] = ss;
      }
    }
    __syncthreads();
    int myb[4];
    for (int k = 0; k < 4; ++k) {
      int i = 4 * t + k;
      int b = (i < B) ? bucketOf(s4[k]) : -1;
      myb[k] = b;
      if (b >= 0) atomicAdd(&cursor[b], 1);
    }
    __syncthreads();
    // exclusive prefix of bucket counts -> bucket starts
    int c0 = cursor[4 * t], c1 = cursor[4 * t + 1], c2 = cursor[4 * t + 2],
        c3 = cursor[4 * t + 3];
    int loc = c0 + c1 + c2 + c3;
    int v = loc;
    for (int off = 1; off < 64; off <<= 1) {
      int u = __shfl_up(v, off, 64);
      if (lane >= off) v += u;
    }
    if (lane == 63) wsi[wid] = v;
    __syncthreads();
    if (t == 0) {
      int run = 0;
      for (int w = 0; w < 16; ++w) { int x = wsi[w]; wsi[w] = run; run += x; }
    }
    __syncthreads();
    int excl = v - loc + wsi[wid];
    cursor[4 * t + 0] = excl;
    cursor[4 * t + 1] = excl + c0;
    cursor[4 * t + 2] = excl + c0 + c1;
    cursor[4 * t + 3] = excl + c0 + c1 + c2;
    __syncthreads();
    // counting-sort scatter; after this cursor[b] = end of bucket b
    for (int k = 0; k < 4; ++k)
      if (myb[k] >= 0) {
        int slot = atomicAdd(&cursor[myb[k]], 1);
        ord[slot] = (unsigned short)(4 * t + k);
      }
    __syncthreads();
    // per-bucket exp sums (thread owns buckets 4t..4t+3), all LDS
    float pv[4];
    for (int k = 0; k < 4; ++k) {
      int bb = 4 * t + k;
      int lo_ = bb ? cursor[bb - 1] : 0;
      int hi_ = cursor[bb];
      float s = 0.f;
      for (int m = lo_; m < hi_; ++m) s += __expf(h_lds[ord[m]]);
      pv[k] = s;
    }
    // inclusive suffix sum over 4096 buckets
    float l3 = pv[3], l2 = pv[2] + l3, l1 = pv[1] + l2, l0 = pv[0] + l1;
    float vA = l0;
    for (int off = 1; off < 64; off <<= 1) {
      float u = __shfl_down(vA, off, 64);
      if (lane + off < 64) vA += u;
    }
    if (lane == 0) wsA[wid] = vA;
    __syncthreads();
    if (t == 0) {
      float r = 0.f;
      for (int w = 15; w >= 0; --w) { float x = wsA[w]; wsA[w] = r; r += x; }
    }
    __syncthreads();
    float tail = (vA - l0) + wsA[wid];
    bs[4 * t + 0] = l0 + tail;
    bs[4 * t + 1] = l1 + tail;
    bs[4 * t + 2] = l2 + tail;
    bs[4 * t + 3] = l3 + tail;
    __syncthreads();
    // per-element log-risk (exact tie handling within own bucket)
    double a = 0.0;
    for (int k = 0; k < 4; ++k) {
      int i = 4 * t + k;
      if (i >= B) break;
      float ci = cen[i];
      if (ci == 0.f) continue;
      float si = s4[k];
      int b = myb[k];
      float T = (b + 1 < NBUK) ? bs[b + 1] : 0.f;
      int lo_ = b ? cursor[b - 1] : 0;
      int hi_ = cursor[b];
      for (int m = lo_; m < hi_; ++m) {
        int j = ord[m];
        if (st_lds[j] >= si) T += __expf(h_lds[j]);
      }
      a += (double)((hv4[k] - __logf(T)) * ci);
    }
    double w = wredsumd(a);
    if (lane == 0) dred[wid] = w;
    __syncthreads();
    if (t == 0) {
      double S = 0;
      for (int w2 = 0; w2 < 16; ++w2) S += dred[w2];
      slots[bid].a = (bid == 0) ? S : 0.0;
      slots[bid].b = (bid == 0) ? 0.0 : S;
      slots[bid].c = 0u;
      slots[bid].d = 0u;
      __hip_atomic_store(&slots[bid].flag, FLAG_MAGIC, __ATOMIC_RELEASE,
                         __HIP_MEMORY_SCOPE_AGENT);
    }
  } else {
    // ============ pair-rank loss (specialized LGG / HGG blocks) ===========
    const bool isL = (bid < 2 + NPL);
    const int pb = isL ? (bid - 2) : (bid - 2 - NPL);
    const int NP = isL ? NPL : NPH;
    uint2* pool = (uint2*)smem_i;           // [4096] 32 KB packed records
    float* aLUT = (float*)(smem_i + 8192);  // [81] swish alpha LUT
    int* cnts = (int*)(aLUT + 81);          // [4]: counts + cursors
    const float beta = isL ? b1p[0] : b2p[0];
    const int athr = isL ? 40 : 65;

    if (t < 81) {
      int dy = t / 9, dq = t - 9 * dy;
      float d = (RISK[dq] - RISK[dy]) * 0.125f;
      aLUT[t] = d / (1.f + __expf(-beta * d));  // swish(d, beta)
    }
    if (t < 4) cnts[t] = 0;
    __syncthreads();
    // classify (vectorized loads); cat 0 = young, 1 = old, -1 = skip
    int av4[4], cat[4];
    if (4 * t + 3 < B) {
      int4 av = ((const int4*)age)[t];
      int4 gv = ((const int4*)grade)[t];
      av4[0] = av.x; av4[1] = av.y; av4[2] = av.z; av4[3] = av.w;
      int gv4[4] = {gv.x, gv.y, gv.z, gv.w};
      for (int k = 0; k < 4; ++k) {
        bool ok = isL ? (gv4[k] == 0) : (gv4[k] == 1 || gv4[k] == 2);
        cat[k] = ok ? (av4[k] < athr ? 0 : 1) : -1;
      }
    } else {
      for (int k = 0; k < 4; ++k) {
        int i = 4 * t + k;
        cat[k] = -1;
        av4[k] = 0;
        if (i < B) {
          int g = grade[i];
          av4[k] = age[i];
          bool ok = isL ? (g == 0) : (g == 1 || g == 2);
          if (ok) cat[k] = (av4[k] < athr) ? 0 : 1;
        }
      }
    }
    for (int k = 0; k < 4; ++k)
      if (cat[k] >= 0) atomicAdd(&cnts[cat[k]], 1);
    __syncthreads();
    const int ny = cnts[0], no = cnts[1];
    if (t == 0) { cnts[2] = 0; cnts[3] = ny; }
    __syncthreads();
    for (int k = 0; k < 4; ++k) {
      int c = cat[k];
      if (c >= 0) {
        int i = 4 * t + k;
        int slot = atomicAdd(&cnts[2 + c], 1);
        pool[slot] = make_uint2(__float_as_uint(h3[i]),
                                (unsigned)((i << 4) | decadeOf(av4[k])));
      }
    }
    __syncthreads();

    double tot = 0.0;
    unsigned int n = 0;
    // youngs strided across blocks, olds strided across threads
    for (int yi = pb; yi < ny; yi += NP) {
      uint2 yr = pool[yi];
      float h3y = __uint_as_float(yr.x);
      int iy = (int)(yr.y >> 4);
      const float* aRow = &aLUT[(yr.y & 15u) * 9];
      for (int oi = t; oi < no; oi += TPB) {
        uint2 orc = pool[ny + oi];
        if ((int)(orc.y >> 4) > iy) {
          float x = aRow[orc.y & 15u] * (h3y - __uint_as_float(orc.x));
          float sp = fmaxf(x, 0.f) + __logf(1.f + __expf(-fabsf(x)));
          tot += (double)sp;
          n++;
        }
      }
    }
    double wt = wredsumd(tot);
    unsigned int un = wredsumu(n);
    if (lane == 0) { dred[wid] = wt; ured[wid] = un; }
    __syncthreads();
    if (t == 0) {
      double S = 0;
      unsigned int N = 0;
      for (int w = 0; w < 16; ++w) { S += dred[w]; N += ured[w]; }
      slots[bid].a = isL ? S : 0.0;
      slots[bid].b = isL ? 0.0 : S;
      slots[bid].c = isL ? N : 0u;
      slots[bid].d = isL ? 0u : N;
      __hip_atomic_store(&slots[bid].flag, FLAG_MAGIC, __ATOMIC_RELEASE,
                         __HIP_MEMORY_SCOPE_AGENT);
    }
  }

  // ============ block 0, wave 0: spin on all slots, finalize ============
  // All 96 blocks are co-resident (96 << 256 CUs): spin cannot deadlock.
  if (bid == 0 && wid == 0) {
    double s3 = 0, s1 = 0, tl = 0, th = 0;
    unsigned long long nl = 0, nh = 0;
    for (int s = lane; s < NSLOT; s += 64) {
      while (__hip_atomic_load(&slots[s].flag, __ATOMIC_ACQUIRE,
                               __HIP_MEMORY_SCOPE_AGENT) != FLAG_MAGIC)
        __builtin_amdgcn_s_sleep(8);
      double a = slots[s].a;
      double b = slots[s].b;
      unsigned int c = slots[s].c;
      unsigned int d = slots[s].d;
      if (s < 2) {
        s3 += a;
        s1 += b;
      } else {
        tl += a;
        th += b;
        nl += c;
        nh += d;
      }
    }
    for (int off = 32; off; off >>= 1) {
      s3 += __shfl_down(s3, off, 64);
      s1 += __shfl_down(s1, off, 64);
      tl += __shfl_down(tl, off, 64);
      th += __shfl_down(th, off, 64);
      nl += __shfl_down(nl, off, 64);
      nh += __shfl_down(nh, off, 64);
    }
    if (lane == 0) {
      float loss3d = (float)(-s3 / (double)B);
      float loss1d = (float)(-s1 / (double)B);
      float lgg = nl ? (float)(tl / (double)nl) : 0.f;
      float hgg = nh ? (float)(th / (double)nh) : 0.f;
      float losscli = lgg + hgg;
      float v0 = vars[0], v2 = vars[2], v3 = vars[3];
      float r = 0.5f * loss3d / (v0 * v0) + logf(v0);
      r += 0.5f * loss1d / (v2 * v2) + logf(v2);
      r += 0.5f * losscli / (v3 * v3) + logf(v3);
      out[0] = r;
    }
  }
}

extern "C" void kernel_launch(void* const* d_in, const int* in_sizes, int n_in,
                              void* d_out, int out_size, void* d_ws,
                              size_t ws_size, hipStream_t stream) {
  const float* h3 = (const float*)d_in[0];
  const float* h1 = (const float*)d_in[1];
  const float* st = (const float*)d_in[2];
  const float* cen = (const float*)d_in[3];
  const float* vars = (const float*)d_in[4];
  const float* beta1 = (const float*)d_in[5];
  const float* beta2 = (const float*)d_in[6];
  const int* age = (const int*)d_in[7];
  const int* grade = (const int*)d_in[8];
  const int B = in_sizes[0];

  Slot* slots = (Slot*)d_ws;  // every slot written unconditionally: no init
  float* out = (float*)d_out;

  fused_kernel<<<NSLOT, TPB, 0, stream>>>(h3, h1, st, cen, age, grade, beta1,
                                          beta2, vars, slots, out, B);
}